// Round 1
// baseline (157.362 us; speedup 1.0000x reference)
//
#include <hip/hip_runtime.h>

// SVF: linear time-varying 2-state recurrence, parallelized as an
// associative scan over affine maps (A, b):  s_t = A_t s_{t-1} + b_t.
// Single fused kernel: 64 rows x 16 chunks = 1024 blocks (exactly the
// 4-block/CU residency capacity at 256 thr, <=128 VGPR). Inter-chunk
// prefix state flows through device-scope release/acquire flags instead
// of a second kernel pass, eliminating the duplicated input reads,
// duplicated local reduce, duplicated block scan, and the launch drain.

#define BATCH     64
#define SEQ       32768
#define CHUNKS    16
#define CHUNK_LEN (SEQ / CHUNKS)    // 2048
#define TPB       256
#define STEPS     (CHUNK_LEN / TPB) // 8
#define NBLK      (BATCH * CHUNKS)  // 1024

struct Aff { float a00, a01, a10, a11, b0, b1; };

// Apply 'e' (earlier) first, then 'l' (later).
__device__ __forceinline__ Aff compose(const Aff l, const Aff e) {
    Aff r;
    r.a00 = fmaf(l.a00, e.a00, l.a01 * e.a10);
    r.a01 = fmaf(l.a00, e.a01, l.a01 * e.a11);
    r.a10 = fmaf(l.a10, e.a00, l.a11 * e.a10);
    r.a11 = fmaf(l.a10, e.a01, l.a11 * e.a11);
    r.b0  = fmaf(l.a00, e.b0, fmaf(l.a01, e.b1, l.b0));
    r.b1  = fmaf(l.a10, e.b0, fmaf(l.a11, e.b1, l.b1));
    return r;
}

__device__ __forceinline__ Aff step_affine(float gi, float Ri, float xi) {
    float T  = 1.0f / fmaf(gi, gi + Ri, 1.0f);   // 1/(1+g*(g+2R))
    float Tg = T * gi;
    Aff r;
    r.a00 = 2.0f * T - 1.0f;
    r.a01 = -2.0f * Tg;
    r.a10 = 2.0f * Tg;
    r.a11 = 2.0f * fmaf(Tg, Ri, T) - 1.0f;       // 2*T*(2R*g+1)-1
    r.b0  = 2.0f * Tg * xi;
    r.b1  = gi * r.b0;
    return r;
}

// Order-preserving inclusive Hillis-Steele scan over the block (time order =
// thread order). Double-buffered: 1 barrier per level, 8 levels. After the
// final barrier, buf[0][t] holds the inclusive result for every t.
__device__ __forceinline__ Aff block_scan_incl(Aff v, Aff (*buf)[TPB], int t) {
    int src = 0;
    buf[0][t] = v;
    __syncthreads();
#pragma unroll
    for (int off = 1; off < TPB; off <<= 1) {
        Aff cur = buf[src][t];
        int idx = (t >= off) ? (t - off) : 0;    // clamped: safe speculative read
        Aff prev = buf[src][idx];
        Aff res = (t >= off) ? compose(cur, prev) : cur;
        buf[1 - src][t] = res;
        src ^= 1;
        __syncthreads();
    }
    return buf[src][t];   // src == 0 after 8 levels
}

__device__ __forceinline__ void load8(const float* __restrict__ p, int base, float v[8]) {
    float4 a = *reinterpret_cast<const float4*>(p + base);
    float4 b = *reinterpret_cast<const float4*>(p + base + 4);
    v[0]=a.x; v[1]=a.y; v[2]=a.z; v[3]=a.w; v[4]=b.x; v[5]=b.y; v[6]=b.z; v[7]=b.w;
}

__global__ __launch_bounds__(TPB, 4) void svf_fused(
    const float* __restrict__ audio, const float* __restrict__ g,
    const float* __restrict__ twoR, const float* __restrict__ mix,
    float* __restrict__ out,
    unsigned int* __restrict__ flags, Aff* __restrict__ chunk_aff)
{
    __shared__ Aff buf[2][TPB];
    __shared__ float pred[CHUNKS - 1][6];
    __shared__ float cs_sh[2];

    const int blk  = blockIdx.x;
    const int b    = blk >> 4;              // row (CHUNKS == 16)
    const int c    = blk & (CHUNKS - 1);    // chunk within row
    const int t    = threadIdx.x;
    const int base = blk * CHUNK_LEN + t * STEPS;

    float gv[STEPS], rv[STEPS], xv[STEPS];
    load8(g, base, gv); load8(twoR, base, rv); load8(audio, base, xv);

    Aff acc = step_affine(gv[0], rv[0], xv[0]);
#pragma unroll
    for (int i = 1; i < STEPS; ++i)
        acc = compose(step_affine(gv[i], rv[i], xv[i]), acc);

    // Prefetch mix now: its HBM latency hides under the scan + flag wait.
    // mix: [B,N,3] -> 24 consecutive floats per thread, 16B-aligned.
    const float4* m4 = reinterpret_cast<const float4*>(mix + 3 * base);
    float mv[24];
#pragma unroll
    for (int q = 0; q < 6; ++q) {
        float4 m = m4[q];
        mv[4*q+0]=m.x; mv[4*q+1]=m.y; mv[4*q+2]=m.z; mv[4*q+3]=m.w;
    }

    Aff incl = block_scan_incl(acc, buf, t);
    // buf[0][t] == incl for all t (valid after the scan's final barrier).

    // Publish this chunk's whole-chunk affine (last chunk of a row has no
    // consumer). Release at agent scope makes the Aff stores visible
    // across XCDs before the flag flips.
    if (t == TPB - 1 && c < CHUNKS - 1) {
        chunk_aff[blk] = incl;
        __threadfence();
        __hip_atomic_store(&flags[blk], 1u, __ATOMIC_RELEASE, __HIP_MEMORY_SCOPE_AGENT);
    }

    // Threads 0..c-1 each acquire one predecessor chunk affine (parallel
    // waits; dependencies point only at lower blockIdx -> no deadlock, and
    // all 1024 blocks are co-resident anyway).
    if (t < c) {
        const int cc = b * CHUNKS + t;
        while (__hip_atomic_load(&flags[cc], __ATOMIC_ACQUIRE,
                                 __HIP_MEMORY_SCOPE_AGENT) == 0u) {
            __builtin_amdgcn_s_sleep(1);
        }
        Aff a = chunk_aff[cc];
        pred[t][0] = a.a00; pred[t][1] = a.a01; pred[t][2] = a.a10;
        pred[t][3] = a.a11; pred[t][4] = a.b0;  pred[t][5] = a.b1;
    }
    __syncthreads();

    // Chunk start state: apply predecessor chunk affines in time order.
    if (t == 0) {
        float s0 = 1.0f, s1 = 1.0f;   // s0 = ones(2)
        for (int j = 0; j < c; ++j) {
            float n0 = fmaf(pred[j][0], s0, fmaf(pred[j][1], s1, pred[j][4]));
            float n1 = fmaf(pred[j][2], s0, fmaf(pred[j][3], s1, pred[j][5]));
            s0 = n0; s1 = n1;
        }
        cs_sh[0] = s0; cs_sh[1] = s1;
    }
    __syncthreads();

    const float cs0 = cs_sh[0], cs1 = cs_sh[1];

    // Thread segment start state = exclusive prefix applied to chunk start.
    float s0, s1;
    if (t == 0) { s0 = cs0; s1 = cs1; }
    else {
        Aff p = buf[0][t - 1];
        s0 = fmaf(p.a00, cs0, fmaf(p.a01, cs1, p.b0));
        s1 = fmaf(p.a10, cs0, fmaf(p.a11, cs1, p.b1));
    }

    float ov[STEPS];
#pragma unroll
    for (int i = 0; i < STEPS; ++i) {
        float gi = gv[i], Ri = rv[i], xi = xv[i];
        float T  = 1.0f / fmaf(gi, gi + Ri, 1.0f);
        float w  = fmaf(gi, xi, s0);                         // g*x + s0
        float Y0 = T * fmaf(-gi, s1, w);                     // bp
        float Y1 = T * fmaf(gi, w, fmaf(Ri, gi, 1.0f) * s1); // lp
        float hp = xi - Ri * Y0 - Y1;
        ov[i] = fmaf(Ri * mv[3*i], Y0, fmaf(mv[3*i+1], Y1, mv[3*i+2] * hp));
        s0 = fmaf(2.0f, Y0, -s0);
        s1 = fmaf(2.0f, Y1, -s1);
    }

    *reinterpret_cast<float4*>(out + base)     = make_float4(ov[0], ov[1], ov[2], ov[3]);
    *reinterpret_cast<float4*>(out + base + 4) = make_float4(ov[4], ov[5], ov[6], ov[7]);
}

extern "C" void kernel_launch(void* const* d_in, const int* in_sizes, int n_in,
                              void* d_out, int out_size, void* d_ws, size_t ws_size,
                              hipStream_t stream) {
    const float* audio = (const float*)d_in[0];
    const float* g     = (const float*)d_in[1];
    const float* twoR  = (const float*)d_in[2];
    const float* mix   = (const float*)d_in[3];
    float* out = (float*)d_out;

    // ws layout: [flags: 1024 u32 = 4 KB][chunk_aff: 1024 Aff = 24 KB]
    unsigned int* flags = (unsigned int*)d_ws;
    Aff* chunk_aff = (Aff*)((char*)d_ws + NBLK * sizeof(unsigned int));

    // Harness poisons ws between iterations: flags must be zeroed each launch.
    hipMemsetAsync(flags, 0, NBLK * sizeof(unsigned int), stream);

    svf_fused<<<NBLK, TPB, 0, stream>>>(audio, g, twoR, mix, out, flags, chunk_aff);
}

// Round 4
// 149.823 us; speedup vs baseline: 1.0503x; 1.0503x over previous
//
#include <hip/hip_runtime.h>

// SVF: linear time-varying 2-state recurrence as an associative scan over
// affine maps (A,b): s_t = A_t s_{t-1} + b_t.
//
// ONE ROW PER BLOCK. 64 blocks x 1024 threads, 32 timesteps/thread:
//   phase 1: streaming per-thread reduce (32 steps -> one Aff in regs)
//   phase 2: 10-level double-buffered Hillis-Steele scan in LDS
//   phase 3: apply exclusive prefix to s_init=(1,1), stream emit
//
// Round-3 post-mortem: every cross-block handshake variant (agent-scope
// acquire spin, memory-side RMW poll, cooperative grid.sync) either
// stormed L2 coherence, hung the container, or silently failed. And the
// harness's 256 MiB d_ws re-poison fill (~44 us) is billed inside the
// timed region. One-row-per-block removes BOTH: no workspace, no memset,
// no cross-block communication, single plain launch. Phase-3 re-reads of
// g/twoR/audio are L2-resident (8 blocks/XCD x 384 KB = 3 MB < 4 MB L2).

#define BATCH 64
#define SEQ   32768
#define TPB   1024
#define STEPS (SEQ / TPB)    // 32
#define QUADS (STEPS / 4)    // 8

struct Aff { float a00, a01, a10, a11, b0, b1; };

// Apply 'e' (earlier) first, then 'l' (later).
__device__ __forceinline__ Aff compose(const Aff l, const Aff e) {
    Aff r;
    r.a00 = fmaf(l.a00, e.a00, l.a01 * e.a10);
    r.a01 = fmaf(l.a00, e.a01, l.a01 * e.a11);
    r.a10 = fmaf(l.a10, e.a00, l.a11 * e.a10);
    r.a11 = fmaf(l.a10, e.a01, l.a11 * e.a11);
    r.b0  = fmaf(l.a00, e.b0, fmaf(l.a01, e.b1, l.b0));
    r.b1  = fmaf(l.a10, e.b0, fmaf(l.a11, e.b1, l.b1));
    return r;
}

__device__ __forceinline__ Aff step_affine(float gi, float Ri, float xi) {
    float T  = 1.0f / fmaf(gi, gi + Ri, 1.0f);   // 1/(1+g*(g+2R))
    float Tg = T * gi;
    Aff r;
    r.a00 = 2.0f * T - 1.0f;
    r.a01 = -2.0f * Tg;
    r.a10 = 2.0f * Tg;
    r.a11 = 2.0f * fmaf(Tg, Ri, T) - 1.0f;       // 2*T*(2R*g+1)-1
    r.b0  = 2.0f * Tg * xi;
    r.b1  = gi * r.b0;
    return r;
}

__device__ __forceinline__ Aff quad_affine(float4 gq, float4 rq, float4 xq) {
    Aff a = step_affine(gq.x, rq.x, xq.x);
    a = compose(step_affine(gq.y, rq.y, xq.y), a);
    a = compose(step_affine(gq.z, rq.z, xq.z), a);
    a = compose(step_affine(gq.w, rq.w, xq.w), a);
    return a;
}

__device__ __forceinline__ float emit1(float gi, float Ri, float xi,
                                       float m0, float m1, float m2,
                                       float& s0, float& s1) {
    float T  = 1.0f / fmaf(gi, gi + Ri, 1.0f);
    float w  = fmaf(gi, xi, s0);                         // g*x + s0
    float Y0 = T * fmaf(-gi, s1, w);                     // bp
    float Y1 = T * fmaf(gi, w, fmaf(Ri, gi, 1.0f) * s1); // lp
    float hp = xi - Ri * Y0 - Y1;
    float o  = fmaf(Ri * m0, Y0, fmaf(m1, Y1, m2 * hp));
    s0 = fmaf(2.0f, Y0, -s0);
    s1 = fmaf(2.0f, Y1, -s1);
    return o;
}

__global__ __launch_bounds__(TPB, 4) void svf_row(
    const float* __restrict__ audio, const float* __restrict__ g,
    const float* __restrict__ twoR, const float* __restrict__ mix,
    float* __restrict__ out)
{
    __shared__ Aff buf[2][TPB];   // 48 KB LDS
    const int t    = threadIdx.x;
    const int base = blockIdx.x * SEQ + t * STEPS;

    const float4* g4 = reinterpret_cast<const float4*>(g + base);
    const float4* r4 = reinterpret_cast<const float4*>(twoR + base);
    const float4* x4 = reinterpret_cast<const float4*>(audio + base);

    // Phase 1: streaming reduce, 6-reg accumulator (no 96-float preload;
    // keeps VGPR under the 128 cap from __launch_bounds__).
    Aff acc = quad_affine(g4[0], r4[0], x4[0]);
#pragma unroll 2
    for (int q = 1; q < QUADS; ++q)
        acc = compose(quad_affine(g4[q], r4[q], x4[q]), acc);

    // Phase 2: order-preserving inclusive scan (time order = thread order),
    // double-buffered, 1 barrier/level, 10 levels. Own value carried in
    // registers; only the partner is read from LDS.
    int src = 0;
    buf[0][t] = acc;
    __syncthreads();
#pragma unroll
    for (int off = 1; off < TPB; off <<= 1) {
        Aff prev = buf[src][(t >= off) ? (t - off) : 0];  // clamped speculative
        if (t >= off) acc = compose(acc, prev);
        buf[1 - src][t] = acc;
        src ^= 1;
        __syncthreads();
    }
    // src == 0 after 10 levels; buf[0][t] = inclusive prefix for every t.

    // Phase 3: thread start state = exclusive prefix applied to s_init=(1,1).
    float s0, s1;
    if (t == 0) { s0 = 1.0f; s1 = 1.0f; }
    else {
        Aff p = buf[0][t - 1];
        s0 = p.a00 + p.a01 + p.b0;
        s1 = p.a10 + p.a11 + p.b1;
    }

    // mix: [B,N,3] -> 96 consecutive floats/thread, 16B-aligned (3*base%4==0).
    const float4* m4 = reinterpret_cast<const float4*>(mix + 3 * base);
    float4* o4 = reinterpret_cast<float4*>(out + base);
#pragma unroll 1
    for (int q = 0; q < QUADS; ++q) {
        float4 gq = g4[q], rq = r4[q], xq = x4[q];   // L2-hit re-reads
        float4 ma = m4[3*q+0], mb = m4[3*q+1], mc = m4[3*q+2];
        float4 ov;
        ov.x = emit1(gq.x, rq.x, xq.x, ma.x, ma.y, ma.z, s0, s1);
        ov.y = emit1(gq.y, rq.y, xq.y, ma.w, mb.x, mb.y, s0, s1);
        ov.z = emit1(gq.z, rq.z, xq.z, mb.z, mb.w, mc.x, s0, s1);
        ov.w = emit1(gq.w, rq.w, xq.w, mc.y, mc.z, mc.w, s0, s1);
        o4[q] = ov;
    }
}

extern "C" void kernel_launch(void* const* d_in, const int* in_sizes, int n_in,
                              void* d_out, int out_size, void* d_ws, size_t ws_size,
                              hipStream_t stream) {
    const float* audio = (const float*)d_in[0];
    const float* g     = (const float*)d_in[1];
    const float* twoR  = (const float*)d_in[2];
    const float* mix   = (const float*)d_in[3];
    float* out = (float*)d_out;
    (void)d_ws; (void)ws_size;   // deliberately unused: no workspace, no poison fill

    svf_row<<<BATCH, TPB, 0, stream>>>(audio, g, twoR, mix, out);
}

// Round 5
// 97.366 us; speedup vs baseline: 1.6162x; 1.5388x over previous
//
#include <hip/hip_runtime.h>

// SVF: linear time-varying 2-state recurrence as an associative scan over
// affine maps (A,b): s_t = A_t s_{t-1} + b_t.
//
// Two-kernel structure (the only cross-chunk mechanism that has passed:
// the kernel boundary; rounds 1-3's intra-kernel handshakes all failed).
// 64 rows x 16 chunks = 1024 blocks x 256 thr (full chip, 4 blk/CU).
//
// vs round-0 baseline (95.6 us):
//  * k1 stores each thread's INCLUSIVE prefix affine to ws (8 MB, padded
//    32 B) -- ws use is free: the harness's 256 MiB ws poison fill (~44 us)
//    runs unconditionally (round-4 evidence). k2 then skips the entire
//    redo of the reduce + block scan (~600 VALU inst + 8 barriers/thread).
//  * k1's scan: 6-level in-wave __shfl_up scan + one 4-entry cross-wave
//    LDS combine = 1 barrier total (was 8 barriers, 12.3 KB LDS).
//  * identical blockIdx->chunk mapping in both kernels => k2's re-reads
//    of g/twoR/audio land on the k1-warmed same-XCD L2.

#define BATCH     64
#define SEQ       32768
#define CHUNKS    16
#define CHUNK_LEN (SEQ / CHUNKS)    // 2048
#define TPB       256
#define STEPS     (CHUNK_LEN / TPB) // 8
#define NBLK      (BATCH * CHUNKS)  // 1024

struct Aff { float a00, a01, a10, a11, b0, b1; };

// Apply 'e' (earlier) first, then 'l' (later).
__device__ __forceinline__ Aff compose(const Aff l, const Aff e) {
    Aff r;
    r.a00 = fmaf(l.a00, e.a00, l.a01 * e.a10);
    r.a01 = fmaf(l.a00, e.a01, l.a01 * e.a11);
    r.a10 = fmaf(l.a10, e.a00, l.a11 * e.a10);
    r.a11 = fmaf(l.a10, e.a01, l.a11 * e.a11);
    r.b0  = fmaf(l.a00, e.b0, fmaf(l.a01, e.b1, l.b0));
    r.b1  = fmaf(l.a10, e.b0, fmaf(l.a11, e.b1, l.b1));
    return r;
}

__device__ __forceinline__ Aff step_affine(float gi, float Ri, float xi) {
    float T  = 1.0f / fmaf(gi, gi + Ri, 1.0f);   // 1/(1+g*(g+2R))
    float Tg = T * gi;
    Aff r;
    r.a00 = 2.0f * T - 1.0f;
    r.a01 = -2.0f * Tg;
    r.a10 = 2.0f * Tg;
    r.a11 = 2.0f * fmaf(Tg, Ri, T) - 1.0f;       // 2*T*(2R*g+1)-1
    r.b0  = 2.0f * Tg * xi;
    r.b1  = gi * r.b0;
    return r;
}

__device__ __forceinline__ Aff shfl_up_aff(const Aff v, int delta) {
    Aff r;
    r.a00 = __shfl_up(v.a00, delta, 64);
    r.a01 = __shfl_up(v.a01, delta, 64);
    r.a10 = __shfl_up(v.a10, delta, 64);
    r.a11 = __shfl_up(v.a11, delta, 64);
    r.b0  = __shfl_up(v.b0,  delta, 64);
    r.b1  = __shfl_up(v.b1,  delta, 64);
    return r;
}

__device__ __forceinline__ void load8(const float* __restrict__ p, int base, float v[8]) {
    float4 a = *reinterpret_cast<const float4*>(p + base);
    float4 b = *reinterpret_cast<const float4*>(p + base + 4);
    v[0]=a.x; v[1]=a.y; v[2]=a.z; v[3]=a.w; v[4]=b.x; v[5]=b.y; v[6]=b.z; v[7]=b.w;
}

// ---------------- kernel 1: reduce + scan, store prefixes ----------------
__global__ __launch_bounds__(TPB, 4) void svf_reduce(
    const float* __restrict__ audio, const float* __restrict__ g,
    const float* __restrict__ twoR,
    float4* __restrict__ pref,        // [NBLK*TPB] x 2 float4 (32 B/thread)
    float4* __restrict__ chunk_comp)  // [NBLK] x 2 float4
{
    __shared__ Aff wtot[TPB / 64];

    const int blk  = blockIdx.x;
    const int t    = threadIdx.x;
    const int lane = t & 63;
    const int wv   = t >> 6;
    const int base = blk * CHUNK_LEN + t * STEPS;

    float gv[STEPS], rv[STEPS], xv[STEPS];
    load8(g, base, gv); load8(twoR, base, rv); load8(audio, base, xv);

    Aff acc = step_affine(gv[0], rv[0], xv[0]);
#pragma unroll
    for (int i = 1; i < STEPS; ++i)
        acc = compose(step_affine(gv[i], rv[i], xv[i]), acc);

    // In-wave inclusive scan (time order = lane order), 6 shuffle levels.
#pragma unroll
    for (int off = 1; off < 64; off <<= 1) {
        Aff p = shfl_up_aff(acc, off);
        if (lane >= off) acc = compose(acc, p);
    }

    // Cross-wave combine: 1 barrier.
    if (lane == 63) wtot[wv] = acc;
    __syncthreads();
    if (wv > 0) {
        Aff wp = wtot[0];
        for (int j = 1; j < wv; ++j) wp = compose(wtot[j], wp);
        acc = compose(acc, wp);
    }

    // Store inclusive prefix (padded to 32 B for aligned float4 stores).
    const int idx = blk * TPB + t;
    pref[2 * idx]     = make_float4(acc.a00, acc.a01, acc.a10, acc.a11);
    pref[2 * idx + 1] = make_float4(acc.b0,  acc.b1,  0.0f,    0.0f);

    if (t == TPB - 1) {   // whole-chunk affine
        chunk_comp[2 * blk]     = make_float4(acc.a00, acc.a01, acc.a10, acc.a11);
        chunk_comp[2 * blk + 1] = make_float4(acc.b0,  acc.b1,  0.0f,    0.0f);
    }
}

// ---------------- kernel 2: prefix lookup + emit ----------------
__global__ __launch_bounds__(TPB, 4) void svf_emit(
    const float* __restrict__ audio, const float* __restrict__ g,
    const float* __restrict__ twoR, const float* __restrict__ mix,
    const float4* __restrict__ pref, const float4* __restrict__ chunk_comp,
    float* __restrict__ out)
{
    const int blk  = blockIdx.x;
    const int b    = blk >> 4;              // row (CHUNKS == 16)
    const int t    = threadIdx.x;
    const int base = blk * CHUNK_LEN + t * STEPS;

    // Issue the thread-prefix load first (latency hides under input loads).
    float4 pA, pB;
    if (t > 0) {
        const int pidx = blk * TPB + t - 1;
        pA = pref[2 * pidx];
        pB = pref[2 * pidx + 1];
    }

    float gv[STEPS], rv[STEPS], xv[STEPS];
    load8(g, base, gv); load8(twoR, base, rv); load8(audio, base, xv);

    // mix: [B,N,3] -> 24 consecutive floats per thread, 16B-aligned.
    const float4* m4 = reinterpret_cast<const float4*>(mix + 3 * base);
    float mv[24];
#pragma unroll
    for (int q = 0; q < 6; ++q) {
        float4 m = m4[q];
        mv[4*q+0]=m.x; mv[4*q+1]=m.y; mv[4*q+2]=m.z; mv[4*q+3]=m.w;
    }

    // Chunk start state: apply predecessor chunk affines in time order
    // (uniform addresses -> scalar broadcast loads, <=15 iterations).
    float cs0 = 1.0f, cs1 = 1.0f;   // s_init = ones(2)
    for (int cc = b * CHUNKS; cc < blk; ++cc) {
        float4 A  = chunk_comp[2 * cc];
        float4 Bv = chunk_comp[2 * cc + 1];
        float n0 = fmaf(A.x, cs0, fmaf(A.y, cs1, Bv.x));
        float n1 = fmaf(A.z, cs0, fmaf(A.w, cs1, Bv.y));
        cs0 = n0; cs1 = n1;
    }

    // Thread segment start state = exclusive prefix applied to chunk start.
    float s0, s1;
    if (t == 0) { s0 = cs0; s1 = cs1; }
    else {
        s0 = fmaf(pA.x, cs0, fmaf(pA.y, cs1, pB.x));
        s1 = fmaf(pA.z, cs0, fmaf(pA.w, cs1, pB.y));
    }

    float ov[STEPS];
#pragma unroll
    for (int i = 0; i < STEPS; ++i) {
        float gi = gv[i], Ri = rv[i], xi = xv[i];
        float T  = 1.0f / fmaf(gi, gi + Ri, 1.0f);
        float w  = fmaf(gi, xi, s0);                         // g*x + s0
        float Y0 = T * fmaf(-gi, s1, w);                     // bp
        float Y1 = T * fmaf(gi, w, fmaf(Ri, gi, 1.0f) * s1); // lp
        float hp = xi - Ri * Y0 - Y1;
        ov[i] = fmaf(Ri * mv[3*i], Y0, fmaf(mv[3*i+1], Y1, mv[3*i+2] * hp));
        s0 = fmaf(2.0f, Y0, -s0);
        s1 = fmaf(2.0f, Y1, -s1);
    }

    *reinterpret_cast<float4*>(out + base)     = make_float4(ov[0], ov[1], ov[2], ov[3]);
    *reinterpret_cast<float4*>(out + base + 4) = make_float4(ov[4], ov[5], ov[6], ov[7]);
}

extern "C" void kernel_launch(void* const* d_in, const int* in_sizes, int n_in,
                              void* d_out, int out_size, void* d_ws, size_t ws_size,
                              hipStream_t stream) {
    const float* audio = (const float*)d_in[0];
    const float* g     = (const float*)d_in[1];
    const float* twoR  = (const float*)d_in[2];
    const float* mix   = (const float*)d_in[3];
    float* out = (float*)d_out;

    // ws layout: [pref: NBLK*TPB*32 B = 8 MB][chunk_comp: NBLK*32 B = 32 KB]
    // No flags, no memset: k2 only reads ws locations k1 wrote this launch;
    // the kernel boundary provides cross-XCD visibility.
    float4* pref       = (float4*)d_ws;
    float4* chunk_comp = (float4*)((char*)d_ws + (size_t)NBLK * TPB * 32);

    svf_reduce<<<NBLK, TPB, 0, stream>>>(audio, g, twoR, pref, chunk_comp);
    svf_emit<<<NBLK, TPB, 0, stream>>>(audio, g, twoR, mix, pref, chunk_comp, out);
}